// Round 2
// baseline (760.783 us; speedup 1.0000x reference)
//
#include <hip/hip_runtime.h>

#define B8 8

typedef __attribute__((ext_vector_type(8))) short short8;
typedef __attribute__((ext_vector_type(4))) float floatx4;

static __device__ __forceinline__ unsigned short f2bf(float f) {
  unsigned int u = __float_as_uint(f);
  unsigned int r = (u + 0x7fffu + ((u >> 16) & 1u)) >> 16;
  return (unsigned short)r;
}

// ---------------------------------------------------------------------------
// weight transform: w[co][ci][3][3] fp32 -> wT[tap][co][ci] bf16
// ---------------------------------------------------------------------------
__global__ __launch_bounds__(256) void wtransform(
    const float* __restrict__ w, unsigned short* __restrict__ wT,
    int Cout, int Cin)
{
  int idx = blockIdx.x * 256 + threadIdx.x;
  if (idx >= Cout * Cin) return;
  int ci = idx % Cin, co = idx / Cin;
  const float* s = w + (size_t)idx * 9;
#pragma unroll
  for (int t = 0; t < 9; ++t)
    wT[((size_t)t * Cout + co) * Cin + ci] = f2bf(s[t]);
}

// elementwise fp32 -> bf16 (for cls1 1x1 weights, layout preserved)
__global__ __launch_bounds__(256) void cvt_bf16(
    const float* __restrict__ w, unsigned short* __restrict__ o, int n)
{
  int i = blockIdx.x * 256 + threadIdx.x;
  if (i < n) o[i] = f2bf(w[i]);
}

// ---------------------------------------------------------------------------
// res2 NCHW fp32 -> NHWC bf16, 4-batch half.  [4,256,128,128] -> [4,128,128,256]
// Tile: 32 ci x 256 px through LDS. Reads coalesced float4 along x; each
// lane writes one pixel's 64B ci-chunk (full cache line). grid = 4*8*64.
// ---------------------------------------------------------------------------
__global__ __launch_bounds__(256) void nchw2nhwc_bf16(
    const float* __restrict__ in, unsigned short* __restrict__ out)
{
  int t = blockIdx.x;
  int pb = t & 63;
  int cb = (t >> 6) & 7;
  int b = t >> 9;                      // local batch 0..3

  __shared__ unsigned short sT[32][260];  // 260 pad: conflict-free both phases

  int tid = threadIdx.x;
  int c4 = tid >> 6;           // 0..3
  int px4 = (tid & 63) << 2;   // 0..252

  const float* ip = in + ((size_t)(b * 256 + cb * 32) * 16384) + pb * 256;
#pragma unroll
  for (int cc = 0; cc < 8; ++cc) {
    int ci = cc * 4 + c4;
    float4 v = *(const float4*)&ip[(size_t)ci * 16384 + px4];
    unsigned int p0 = (unsigned)f2bf(v.x) | ((unsigned)f2bf(v.y) << 16);
    unsigned int p1 = (unsigned)f2bf(v.z) | ((unsigned)f2bf(v.w) << 16);
    *(unsigned int*)&sT[ci][px4] = p0;
    *(unsigned int*)&sT[ci][px4 + 2] = p1;
  }
  __syncthreads();

  int px = tid;
  unsigned short* op =
      out + ((size_t)(b * 16384 + pb * 256 + px) * 256) + cb * 32;
#pragma unroll
  for (int j = 0; j < 4; ++j) {
    short8 o;
#pragma unroll
    for (int k = 0; k < 8; ++k) o[k] = (short)sT[j * 8 + k][px];
    *(short8*)&op[j * 8] = o;
  }
}

// ---------------------------------------------------------------------------
// fused low-level branch (4-batch half): conv3x3 256->48 (bf16 MFMA) + BN +
// ReLU + 1x1 48->16. Input NHWC bf16: B-fragments are 16B-contiguous short8
// loads straight from global (halo 9x tap reuse held in pix[6][3] regs).
// No LDS staging, no barriers in main loop. Epilogue: BN+ReLU in regs, then
// 1x1 via per-lane partials + shfl_xor(16/32) reduce over the 4 q-groups.
// Block = 16x16 tile, 4 waves x 4 rows. grid = 4b * 64 tiles.
// ---------------------------------------------------------------------------
__global__ __launch_bounds__(256, 2) void conv3x3_hi_nhwc(
    const unsigned short* __restrict__ xh,  // [4,128,128,256] bf16 (local b)
    const unsigned short* __restrict__ wT,  // [9,48,256] bf16
    const float* __restrict__ scale, const float* __restrict__ shift,
    const float* __restrict__ w1,           // [16,48] fp32 (c1b 1x1)
    const float* __restrict__ b1,           // [16]
    float* __restrict__ c1)                 // [4,16,128,128] fp32 (local b)
{
  int t = blockIdx.x;
  int tile = t & 63;
  int b = t >> 6;                      // local batch 0..3
  int ty0 = (tile >> 3) << 4, tx0 = (tile & 7) << 4;

  __shared__ float sW1[16 * 48];
  __shared__ float sB1[16];

  int tid = threadIdx.x;
  for (int i = tid; i < 768; i += 256) sW1[i] = w1[i];
  if (tid < 16) sB1[tid] = b1[tid];
  __syncthreads();

  int lane = tid & 63, w = tid >> 6;
  int l15 = lane & 15, q = lane >> 4;

  // 18 unique B pixels/lane: rows rr=0..5 (gy = ty0+w*4-1+rr),
  // cols cc=0..2 (gx = tx0+l15-1+cc). Offsets in elements, valid flags for pad.
  const unsigned short* xb = xh + (size_t)b * 16384 * 256 + q * 8;
  int ofs[6][3];
  bool vv[6][3];
#pragma unroll
  for (int rr = 0; rr < 6; ++rr) {
    int gy = ty0 + w * 4 - 1 + rr;
#pragma unroll
    for (int cc = 0; cc < 3; ++cc) {
      int gx = tx0 + l15 - 1 + cc;
      bool v = (unsigned)gy < 128u && (unsigned)gx < 128u;
      vv[rr][cc] = v;
      ofs[rr][cc] = v ? ((gy * 128 + gx) * 256) : 0;
    }
  }

  floatx4 acc[3][4];
#pragma unroll
  for (int ct = 0; ct < 3; ++ct)
#pragma unroll
    for (int pt = 0; pt < 4; ++pt) acc[ct][pt] = (floatx4){0.f, 0.f, 0.f, 0.f};

  const short8 z8 = (short8){0, 0, 0, 0, 0, 0, 0, 0};

  for (int ci0 = 0; ci0 < 256; ci0 += 32) {
    short8 pix[6][3];
#pragma unroll
    for (int rr = 0; rr < 6; ++rr)
#pragma unroll
      for (int cc = 0; cc < 3; ++cc)
        pix[rr][cc] =
            vv[rr][cc] ? *(const short8*)&xb[ofs[rr][cc] + ci0] : z8;
#pragma unroll
    for (int ky = 0; ky < 3; ++ky) {
#pragma unroll
      for (int kx = 0; kx < 3; ++kx) {
        int tap = ky * 3 + kx;
        const unsigned short* wbase =
            wT + ((size_t)(tap * 48 + l15)) * 256 + ci0 + q * 8;
        short8 af[3];
#pragma unroll
        for (int ct = 0; ct < 3; ++ct)
          af[ct] = *(const short8*)(wbase + ct * 16 * 256);
#pragma unroll
        for (int ct = 0; ct < 3; ++ct)
#pragma unroll
          for (int pt = 0; pt < 4; ++pt)
            acc[ct][pt] = __builtin_amdgcn_mfma_f32_16x16x32_bf16(
                af[ct], pix[pt + ky][kx], acc[ct][pt], 0, 0, 0);
      }
    }
  }

  // BN + ReLU in place (lane holds co = ct*16 + q*4 + r at pixel (w*4+pt,l15))
#pragma unroll
  for (int ct = 0; ct < 3; ++ct) {
#pragma unroll
    for (int r = 0; r < 4; ++r) {
      int c = ct * 16 + q * 4 + r;
      float sc = scale[c], sh = shift[c];
#pragma unroll
      for (int pt = 0; pt < 4; ++pt) {
        float x = fmaf(acc[ct][pt][r], sc, sh);
        acc[ct][pt][r] = x > 0.0f ? x : 0.0f;
      }
    }
  }

  // fused 1x1 (48 -> 16): per-lane partial over its 12 ci, reduce across q
  float* cp = c1 + (size_t)b * 16 * 16384 + (size_t)ty0 * 128 + tx0 + l15;
#pragma unroll
  for (int co = 0; co < 16; ++co) {
    float wv[12];
#pragma unroll
    for (int ct = 0; ct < 3; ++ct)
#pragma unroll
      for (int r = 0; r < 4; ++r)
        wv[ct * 4 + r] = sW1[co * 48 + ct * 16 + q * 4 + r];
    float s[4];
#pragma unroll
    for (int pt = 0; pt < 4; ++pt) {
      float a = 0.0f;
#pragma unroll
      for (int ct = 0; ct < 3; ++ct)
#pragma unroll
        for (int r = 0; r < 4; ++r)
          a = fmaf(wv[ct * 4 + r], acc[ct][pt][r], a);
      a += __shfl_xor(a, 16, 64);
      a += __shfl_xor(a, 32, 64);
      s[pt] = a;
    }
    if (q == (co >> 2)) {
      float bb = sB1[co];
#pragma unroll
      for (int pt = 0; pt < 4; ++pt)
        cp[(size_t)co * 16384 + (w * 4 + pt) * 128] = s[pt] + bb;
    }
  }
}

// ---------------------------------------------------------------------------
// bf16 MFMA conv3x3 on 16x16 spatial, SAME zero pad, K-sliced.
// D[m=co][n=px]; A = wT[tap][co][ci] from global; B = pixels in LDS.
// Software-pipelined: next chunk's 18 loads/thread prefetched into regs
// while current chunk's MFMAs run (grid-limited to 2 blocks/CU, so ILP
// must hide the staging latency).
// grid.x = b * nCoBlk * 2 * nSlice ; part layout [nSlice][B8][Cout][256]
// ---------------------------------------------------------------------------
__global__ __launch_bounds__(256, 2) void conv3x3_mfma(
    const void* __restrict__ inv,          // [B8, Cin, 16, 16] fp32 or bf16
    const unsigned short* __restrict__ wT, // [9, Cout, Cin] bf16
    float* __restrict__ part, int Cin, int Cout, int nCoBlk, int nSlice,
    int inBf16)
{
  int t = blockIdx.x;
  int slice = t % nSlice; t /= nSlice;
  int ph = t & 1; t >>= 1;
  int cb = t % nCoBlk; t /= nCoBlk;
  int b = t;
  int ciSlice = Cin / nSlice;
  int nTiles = ciSlice >> 5;

  __shared__ unsigned short sIn[10 * 18 * 40];

  int tid = threadIdx.x;
  int lane = tid & 63, wave = tid >> 6;
  int wc = wave >> 1, wp = wave & 1;
  int l15 = lane & 15, q = lane >> 4;

  for (int i = tid; i < (10 * 18 * 40) / 2; i += 256) ((unsigned int*)sIn)[i] = 0u;

  floatx4 acc[4][4];
#pragma unroll
  for (int ct = 0; ct < 4; ++ct)
#pragma unroll
    for (int pt = 0; pt < 4; ++pt) acc[ct][pt] = (floatx4){0.f, 0.f, 0.f, 0.f};

  int coBase = cb * 128 + wc * 64;
  int gr0 = ph * 7;
  int sr0 = 1 - ph;

  // per-thread staging slots: 18 elements, offsets hoisted out of the K-loop
  int gofs[18], lofs[18];
#pragma unroll
  for (int k = 0; k < 18; ++k) {
    int i = tid + k * 256;
    int px = i & 15, r9 = i >> 4;
    int rr = r9 % 9, ci = r9 / 9;
    gofs[k] = ci * 256 + (gr0 + rr) * 16 + px;
    lofs[k] = ((sr0 + rr) * 18 + 1 + px) * 40 + ci;
  }
  const float* inbF = (const float*)inv + (size_t)b * Cin * 256;
  const unsigned short* inbU = (const unsigned short*)inv + (size_t)b * Cin * 256;

  unsigned int pf[18];
  {
    int ci0 = slice * ciSlice;
    if (inBf16) {
#pragma unroll
      for (int k = 0; k < 18; ++k) pf[k] = inbU[(size_t)ci0 * 256 + gofs[k]];
    } else {
#pragma unroll
      for (int k = 0; k < 18; ++k)
        pf[k] = __float_as_uint(inbF[(size_t)ci0 * 256 + gofs[k]]);
    }
  }

  for (int ct2 = 0; ct2 < nTiles; ++ct2) {
    int ci0 = slice * ciSlice + ct2 * 32;
    __syncthreads();
    if (inBf16) {
#pragma unroll
      for (int k = 0; k < 18; ++k) sIn[lofs[k]] = (unsigned short)pf[k];
    } else {
#pragma unroll
      for (int k = 0; k < 18; ++k) sIn[lofs[k]] = f2bf(__uint_as_float(pf[k]));
    }
    __syncthreads();
    // prefetch next chunk while MFMAs below execute
    if (ct2 + 1 < nTiles) {
      int cin0 = ci0 + 32;
      if (inBf16) {
#pragma unroll
        for (int k = 0; k < 18; ++k) pf[k] = inbU[(size_t)cin0 * 256 + gofs[k]];
      } else {
#pragma unroll
        for (int k = 0; k < 18; ++k)
          pf[k] = __float_as_uint(inbF[(size_t)cin0 * 256 + gofs[k]]);
      }
    }
#pragma unroll
    for (int ky = 0; ky < 3; ++ky) {
#pragma unroll
      for (int kx = 0; kx < 3; ++kx) {
        int tap = ky * 3 + kx;
        const unsigned short* wbase =
            wT + ((size_t)(tap * Cout + coBase + l15)) * Cin + ci0 + q * 8;
        short8 af[4];
#pragma unroll
        for (int ct = 0; ct < 4; ++ct)
          af[ct] = *(const short8*)(wbase + (size_t)ct * 16 * Cin);
        short8 bf[4];
#pragma unroll
        for (int pt = 0; pt < 4; ++pt) {
          int sRow = wp * 4 + pt + ky;
          int sCol = l15 + kx;
          bf[pt] = *(const short8*)&sIn[(sRow * 18 + sCol) * 40 + q * 8];
        }
#pragma unroll
        for (int ct = 0; ct < 4; ++ct)
#pragma unroll
          for (int pt = 0; pt < 4; ++pt)
            acc[ct][pt] = __builtin_amdgcn_mfma_f32_16x16x32_bf16(
                af[ct], bf[pt], acc[ct][pt], 0, 0, 0);
      }
    }
  }

  float* po = part + ((size_t)(slice * B8 + b) * Cout) * 256;
#pragma unroll
  for (int ct = 0; ct < 4; ++ct) {
#pragma unroll
    for (int pt = 0; pt < 4; ++pt) {
      int co = coBase + ct * 16 + q * 4;
      int px = ph * 128 + wp * 64 + pt * 16 + l15;
#pragma unroll
      for (int r = 0; r < 4; ++r)
        po[(size_t)(co + r) * 256 + px] = acc[ct][pt][r];
    }
  }
}

// ---------------------------------------------------------------------------
// conv1 combine: sum 8 K-slices + BN + ReLU -> x2cat bf16, plus pooled-mean
// broadcast into channels [512,1024). grid.x = B8*512, block=256.
// ---------------------------------------------------------------------------
__global__ __launch_bounds__(256) void combine1(
    const float* __restrict__ part, const float* __restrict__ scale,
    const float* __restrict__ shift, unsigned short* __restrict__ out,
    int Cout, int nSlice, int outStride)
{
  int c = blockIdx.x % Cout, b = blockIdx.x / Cout;
  int tid = threadIdx.x;
  float s = 0.0f;
  for (int sl = 0; sl < nSlice; ++sl)
    s += part[(((size_t)sl * B8 + b) * Cout + c) * 256 + tid];
  float v = fmaf(s, scale[c], shift[c]);
  v = v > 0.0f ? v : 0.0f;
  out[((size_t)b * outStride + c) * 256 + tid] = f2bf(v);
  __shared__ float red[4];
  float w = v;
#pragma unroll
  for (int off = 32; off > 0; off >>= 1) w += __shfl_down(w, off, 64);
  if ((tid & 63) == 0) red[tid >> 6] = w;
  __syncthreads();
  float m = (red[0] + red[1] + red[2] + red[3]) * (1.0f / 256.0f);
  out[((size_t)b * outStride + Cout + c) * 256 + tid] = f2bf(m);
}

// ---------------------------------------------------------------------------
// conv2 combine: sum 4 K-slices + BN + ReLU -> x2T bf16 TRANSPOSED [b][px][ci]
// grid.x = 8b * 16pxg * 4cg ; block 256 = (c16 = tid>>4, px16 = tid&15).
// ---------------------------------------------------------------------------
__global__ __launch_bounds__(256) void combine2T(
    const float* __restrict__ part, const float* __restrict__ scale,
    const float* __restrict__ shift, unsigned short* __restrict__ x2T)
{
  int t = blockIdx.x;
  int cg = t & 3;
  int pxg = (t >> 2) & 15;
  int b = t >> 6;
  int c16 = threadIdx.x >> 4, px16 = threadIdx.x & 15;
  int px = pxg * 16 + px16;
#pragma unroll
  for (int k = 0; k < 4; ++k) {
    int cBase = cg * 256 + k * 64 + c16 * 4;
    unsigned short v4[4];
#pragma unroll
    for (int j = 0; j < 4; ++j) {
      int c = cBase + j;
      float s = 0.0f;
#pragma unroll
      for (int sl = 0; sl < 4; ++sl)
        s += part[(((size_t)sl * B8 + b) * 1024 + c) * 256 + px];
      float v = fmaf(s, scale[c], shift[c]);
      v4[j] = f2bf(v > 0.0f ? v : 0.0f);
    }
    *(ushort2*)&x2T[((size_t)b * 256 + px) * 1024 + cBase] =
        *(ushort2*)&v4[0];
    *(ushort2*)&x2T[((size_t)b * 256 + px) * 1024 + cBase + 2] =
        *(ushort2*)&v4[2];
  }
}

// ---------------------------------------------------------------------------
// cls1 1x1 (1024->4928) as register-only MFMA GEMM. Per batch:
// D[4928co x 256px] = W[4928x1024] * X^T. A & B frags straight from global
// (both 16B-contiguous along ci). grid.x = 77 coBlk * 8 b, block = 4 waves.
// ---------------------------------------------------------------------------
__global__ __launch_bounds__(256, 2) void hyper_gemm(
    const unsigned short* __restrict__ wH,  // [4928,1024] bf16
    const unsigned short* __restrict__ x2T, // [8,256,1024] bf16
    const float* __restrict__ bias,         // [4928]
    float* __restrict__ hyper)              // [8,4928,256] fp32
{
  int cb = blockIdx.x % 77, b = blockIdx.x / 77;
  int tid = threadIdx.x;
  int lane = tid & 63, w = tid >> 6;
  int l15 = lane & 15, q = lane >> 4;

  floatx4 acc[4][4];
#pragma unroll
  for (int ct = 0; ct < 4; ++ct)
#pragma unroll
    for (int pt = 0; pt < 4; ++pt) acc[ct][pt] = (floatx4){0.f, 0.f, 0.f, 0.f};

  const unsigned short* wp0 = wH + ((size_t)(cb * 64 + l15)) * 1024 + q * 8;
  const unsigned short* xp0 =
      x2T + ((size_t)(b * 256 + w * 64 + l15)) * 1024 + q * 8;

  for (int ci0 = 0; ci0 < 1024; ci0 += 32) {
    short8 af[4], bf[4];
#pragma unroll
    for (int ct = 0; ct < 4; ++ct)
      af[ct] = *(const short8*)(wp0 + (size_t)ct * 16 * 1024 + ci0);
#pragma unroll
    for (int pt = 0; pt < 4; ++pt)
      bf[pt] = *(const short8*)(xp0 + (size_t)pt * 16 * 1024 + ci0);
#pragma unroll
    for (int ct = 0; ct < 4; ++ct)
#pragma unroll
      for (int pt = 0; pt < 4; ++pt)
        acc[ct][pt] = __builtin_amdgcn_mfma_f32_16x16x32_bf16(
            af[ct], bf[pt], acc[ct][pt], 0, 0, 0);
  }

#pragma unroll
  for (int ct = 0; ct < 4; ++ct) {
    int co = cb * 64 + ct * 16 + q * 4;
#pragma unroll
    for (int pt = 0; pt < 4; ++pt) {
      int px = w * 64 + pt * 16 + l15;
#pragma unroll
      for (int r = 0; r < 4; ++r)
        hyper[((size_t)b * 4928 + co + r) * 256 + px] = acc[ct][pt][r] + bias[co + r];
    }
  }
}

// ---------------------------------------------------------------------------
// dynamic per-pixel MLP: 18 -> 16 -> 16 -> 256 (see round-0 comments).
// ---------------------------------------------------------------------------
__global__ __launch_bounds__(256) void dyn_mlp(
    const float* __restrict__ hyper, const float* __restrict__ c1,
    const float* __restrict__ catS, const float* __restrict__ catB,
    float* __restrict__ out)
{
  int t = blockIdx.x;
  int q = t & 3;
  int h = (t >> 2) & 15;
  int b = t >> 6;
  int tid = threadIdx.x;
  int xf = tid & 127, r2 = tid >> 7;
  int w = xf >> 3;

  __shared__ float smem[16 * 578];
  __shared__ float sB2[16 * 33];

  const float* hypb = hyper + (size_t)b * 4928 * 256 + h * 16;

  for (int i = tid; i < 576 * 16; i += 256) {
    int ch = i >> 4, ww = i & 15;
    smem[ww * 578 + ch] = hypb[(size_t)ch * 256 + ww];
  }

  float cs[18], cb[18];
#pragma unroll
  for (int i = 0; i < 18; ++i) { cs[i] = catS[i]; cb[i] = catB[i]; }

  float inpv[4][18];
  int yf0 = h * 8 + r2 * 4;
  float cx = (float)(xf & 7) * 0.125f;
#pragma unroll
  for (int k = 0; k < 4; ++k) {
    inpv[k][0] = fmaf(cx, cs[0], cb[0]);
    inpv[k][1] = fmaf((float)((yf0 + k) & 7) * 0.125f, cs[1], cb[1]);
#pragma unroll
    for (int ci = 0; ci < 16; ++ci) {
      float v = c1[((size_t)b * 16 + ci) * 16384 + (size_t)(yf0 + k) * 128 + xf];
      inpv[k][2 + ci] = fmaf(v, cs[2 + ci], cb[2 + ci]);
    }
  }
  __syncthreads();

  const float* sw = smem + w * 578;
  float h0v[4][16];
  {
    const float2* w0p = (const float2*)sw;
#pragma unroll
    for (int co = 0; co < 16; ++co) {
      float a0 = sw[288 + co], a1 = a0, a2 = a0, a3 = a0;
#pragma unroll
      for (int c2 = 0; c2 < 9; ++c2) {
        float2 wv = w0p[co * 9 + c2];
        a0 = fmaf(wv.x, inpv[0][2 * c2], a0); a0 = fmaf(wv.y, inpv[0][2 * c2 + 1], a0);
        a1 = fmaf(wv.x, inpv[1][2 * c2], a1); a1 = fmaf(wv.y, inpv[1][2 * c2 + 1], a1);
        a2 = fmaf(wv.x, inpv[2][2 * c2], a2); a2 = fmaf(wv.y, inpv[2][2 * c2 + 1], a2);
        a3 = fmaf(wv.x, inpv[3][2 * c2], a3); a3 = fmaf(wv.y, inpv[3][2 * c2 + 1], a3);
      }
      h0v[0][co] = fmaxf(a0, 0.0f); h0v[1][co] = fmaxf(a1, 0.0f);
      h0v[2][co] = fmaxf(a2, 0.0f); h0v[3][co] = fmaxf(a3, 0.0f);
    }
  }
  float h1v[4][16];
  {
    const float2* w1p = (const float2*)(sw + 304);
#pragma unroll
    for (int co = 0; co < 16; ++co) {
      float a0 = sw[560 + co], a1 = a0, a2 = a0, a3 = a0;
#pragma unroll
      for (int c2 = 0; c2 < 8; ++c2) {
        float2 wv = w1p[co * 8 + c2];
        a0 = fmaf(wv.x, h0v[0][2 * c2], a0); a0 = fmaf(wv.y, h0v[0][2 * c2 + 1], a0);
        a1 = fmaf(wv.x, h0v[1][2 * c2], a1); a1 = fmaf(wv.y, h0v[1][2 * c2 + 1], a1);
        a2 = fmaf(wv.x, h0v[2][2 * c2], a2); a2 = fmaf(wv.y, h0v[2][2 * c2 + 1], a2);
        a3 = fmaf(wv.x, h0v[3][2 * c2], a3); a3 = fmaf(wv.y, h0v[3][2 * c2 + 1], a3);
      }
      h1v[0][co] = fmaxf(a0, 0.0f); h1v[1][co] = fmaxf(a1, 0.0f);
      h1v[2][co] = fmaxf(a2, 0.0f); h1v[3][co] = fmaxf(a3, 0.0f);
    }
  }

  for (int chunk = 0; chunk < 2; ++chunk) {
    int po0 = q * 64 + chunk * 32;
    __syncthreads();
    for (int i = tid; i < 8192; i += 256) {
      int ch = i >> 4, ww = i & 15;
      smem[ww * 518 + ch] = hypb[(size_t)(576 + po0 * 16 + ch) * 256 + ww];
    }
    for (int i = tid; i < 512; i += 256) {
      int po = i >> 4, ww = i & 15;
      sB2[ww * 33 + po] = hypb[(size_t)(4672 + po0 + po) * 256 + ww];
    }
    __syncthreads();
    const float2* w2p = (const float2*)(smem + w * 518);
    const float* sb2 = sB2 + w * 33;
#pragma unroll 4
    for (int po = 0; po < 32; ++po) {
      float a0 = sb2[po], a1 = a0, a2 = a0, a3 = a0;
#pragma unroll
      for (int c2 = 0; c2 < 8; ++c2) {
        float2 wv = w2p[po * 8 + c2];
        a0 = fmaf(wv.x, h1v[0][2 * c2], a0); a0 = fmaf(wv.y, h1v[0][2 * c2 + 1], a0);
        a1 = fmaf(wv.x, h1v[1][2 * c2], a1); a1 = fmaf(wv.y, h1v[1][2 * c2 + 1], a1);
        a2 = fmaf(wv.x, h1v[2][2 * c2], a2); a2 = fmaf(wv.y, h1v[2][2 * c2 + 1], a2);
        a3 = fmaf(wv.x, h1v[3][2 * c2], a3); a3 = fmaf(wv.y, h1v[3][2 * c2 + 1], a3);
      }
      size_t ob = ((size_t)b * 256 + po0 + po) * 16384 + (size_t)yf0 * 128 + xf;
      out[ob] = a0; out[ob + 128] = a1; out[ob + 256] = a2; out[ob + 384] = a3;
    }
  }
}

// ---------------------------------------------------------------------------
extern "C" void kernel_launch(void* const* d_in, const int* in_sizes, int n_in,
                              void* d_out, int out_size, void* d_ws, size_t ws_size,
                              hipStream_t stream) {
  const float* res5 = (const float*)d_in[0];
  const float* res2 = (const float*)d_in[1];
  const float* bw   = (const float*)d_in[2];
  const float* bn1s = (const float*)d_in[3];
  const float* bn1b = (const float*)d_in[4];
  const float* c0w  = (const float*)d_in[5];
  const float* bn2s = (const float*)d_in[6];
  const float* bn2b = (const float*)d_in[7];
  const float* cls1w = (const float*)d_in[8];
  const float* cls1b = (const float*)d_in[9];
  const float* c1aw = (const float*)d_in[10];
  const float* bn3s = (const float*)d_in[11];
  const float* bn3b = (const float*)d_in[12];
  const float* c1bw = (const float*)d_in[13];
  const float* c1bb = (const float*)d_in[14];
  const float* catS = (const float*)d_in[15];
  const float* catB = (const float*)d_in[16];
  float* out = (float*)d_out;
  float* ws = (float*)d_ws;

  // ws layout (float offsets), lifetime-aliased, peak 25,296,896 fl = 101.2 MB
  //   [0,        2,097,152)  c1        (written after conv2; live to dyn_mlp)
  //   [2,097,152 2,152,448)  wT48      (written after hyper_gemm)
  //   [0,        4,718,592)  wT2u      (dead after conv2)
  //   [4,718,592 5,767,168)  x2cat     (dead after conv2)
  //   [5,767,168 6,815,744)  x2T       (dead after hyper_gemm)
  //   [6,815,744 16,908,288) hyper     (written by hyper_gemm; live to dyn_mlp)
  //                          wT1u alias (dead after conv1)
  //   [16,908,288 25,296,896) partial  (dead after combine2T)
  //                           wH alias (dead after hyper_gemm)
  //                           x2nhwc alias (low branch, 4-batch half = 8,388,608 fl)
  unsigned short* wT2u  = (unsigned short*)(ws);
  float* c1             = ws;                                // alias, post-conv2
  unsigned short* wT48  = (unsigned short*)(ws + 2097152);   // alias, post-conv2
  unsigned short* x2cat = (unsigned short*)(ws + 4718592);
  unsigned short* x2T   = (unsigned short*)(ws + 5767168);
  float* hyper          = ws + 6815744;
  unsigned short* wT1u  = (unsigned short*)(ws + 6815744);   // alias (pre-hyper)
  float* partial        = ws + 16908288;
  unsigned short* wH    = (unsigned short*)(ws + 16908288);  // alias (post-combine2T)
  unsigned short* x2nhwc = (unsigned short*)(ws + 16908288); // alias (post-hyper_gemm)

  // ---- high-level branch ----
  wtransform<<<(512 * 2048 + 255) / 256, 256, 0, stream>>>(bw, wT1u, 512, 2048);
  wtransform<<<(1024 * 1024 + 255) / 256, 256, 0, stream>>>(c0w, wT2u, 1024, 1024);
  conv3x3_mfma<<<8 * 4 * 2 * 8, 256, 0, stream>>>(res5, wT1u, partial, 2048, 512, 4, 8, 0);
  combine1<<<8 * 512, 256, 0, stream>>>(partial, bn1s, bn1b, x2cat, 512, 8, 1024);
  conv3x3_mfma<<<8 * 8 * 2 * 4, 256, 0, stream>>>(x2cat, wT2u, partial, 1024, 1024, 8, 4, 1);
  combine2T<<<8 * 16 * 4, 256, 0, stream>>>(partial, bn2s, bn2b, x2T);
  cvt_bf16<<<(4928 * 1024 + 255) / 256, 256, 0, stream>>>(cls1w, wH, 4928 * 1024);
  hyper_gemm<<<77 * 8, 256, 0, stream>>>(wH, x2T, cls1b, hyper);

  // ---- low-level branch (two 4-batch halves through the dead partial region) ----
  wtransform<<<(48 * 256 + 255) / 256, 256, 0, stream>>>(c1aw, wT48, 48, 256);
  for (int half = 0; half < 2; ++half) {
    nchw2nhwc_bf16<<<4 * 8 * 64, 256, 0, stream>>>(
        res2 + (size_t)half * 4 * 256 * 16384, x2nhwc);
    conv3x3_hi_nhwc<<<4 * 64, 256, 0, stream>>>(
        x2nhwc, wT48, bn3s, bn3b, c1bw, c1bb,
        c1 + (size_t)half * 4 * 16 * 16384);
  }

  // ---- dynamic MLP ----
  dyn_mlp<<<8 * 16 * 4, 256, 0, stream>>>(hyper, c1, catS, catB, out);
}